// Round 5
// baseline (206.570 us; speedup 1.0000x reference)
//
#include <hip/hip_runtime.h>
#include <stdint.h>

typedef unsigned short u16;
typedef _Float16 half8 __attribute__((ext_vector_type(8)));
typedef _Float16 half2t __attribute__((ext_vector_type(2)));
typedef float    f32x4 __attribute__((ext_vector_type(4)));

#define NN 4096
#define SCALE_S 1.2011224087f   // sqrt(log2 e): applied to kq once -> logits in log2 domain

__device__ __forceinline__ u16 f2h(float f) {
    _Float16 h = (_Float16)f;
    return __builtin_bit_cast(u16, h);
}
__device__ __forceinline__ unsigned int pk(u16 a, u16 b) {
    return (unsigned int)a | ((unsigned int)b << 16);
}
__device__ __forceinline__ uint2 pk4h(float a, float b, float c, float d) {
    uint2 r;
    r.x = __builtin_bit_cast(unsigned int, __builtin_amdgcn_cvt_pkrtz(a, b));
    r.y = __builtin_bit_cast(unsigned int, __builtin_amdgcn_cvt_pkrtz(c, d));
    return r;
}
__device__ __forceinline__ void dma16(const u16* src, const u16* dst) {
    __builtin_amdgcn_global_load_lds(
        (const __attribute__((address_space(1))) uint32_t*)src,
        (__attribute__((address_space(3))) uint32_t*)dst, 16, 0, 0);
}

// chunk16 layout for M[d][p] (d = K-dim, inner-8): el = (p>>4)*(2*D) + (d>>3)*128 + (p&15)*8 + (d&7)
// -> MFMA A/B frag reads and DMA stages are all "uniform base + lane*16B".

// ---------------------------------------------------------------------------
// Kernel 0: weights fp32 -> fp16 chunk16. wA=[w_kq;w_v] [256 m][256 c]; wo [256][128].
// ---------------------------------------------------------------------------
__global__ __launch_bounds__(256) void wcast_kernel(
    const float* __restrict__ wkq, const float* __restrict__ wv,
    const float* __restrict__ wo, u16* __restrict__ wA, u16* __restrict__ woh)
{
    const int gid = blockIdx.x * 256 + threadIdx.x;   // 12288 total
    if (gid < 8192) {
        const int m = gid >> 5, co = gid & 31;
        const float* src = (m < 128) ? &wkq[m * 256 + co * 8] : &wv[(m - 128) * 256 + co * 8];
        u16 h[8];
#pragma unroll
        for (int i = 0; i < 8; ++i) h[i] = f2h(src[i]);
        *(uint4*)(wA + (m >> 4) * 4096 + co * 128 + (m & 15) * 8) =
            make_uint4(pk(h[0],h[1]), pk(h[2],h[3]), pk(h[4],h[5]), pk(h[6],h[7]));
    } else {
        const int u = gid - 8192;
        const int m = u >> 4, co = u & 15;
        const float* src = &wo[m * 128 + co * 8];
        u16 h[8];
#pragma unroll
        for (int i = 0; i < 8; ++i) h[i] = f2h(src[i]);
        *(uint4*)(woh + (m >> 4) * 2048 + co * 128 + (m & 15) * 8) =
            make_uint4(pk(h[0],h[1]), pk(h[2],h[3]), pk(h[4],h[5]), pk(h[6],h[7]));
    }
}

// ---------------------------------------------------------------------------
// Kernel 1: [kq ; v] = wA @ x + bias, single-term fp16 MFMA. x cast in-kernel.
// Block: M=256 x N=64 pos, K=256 over 4 iters of 64c. Grid 512 -> 2 blocks/CU.
//   waves 0-3: kq rows (A=w, B=x) -> kqh chunk16 [pos][c=m]
//   waves 4-7: v as x@wv^T (A=x, B=wv) -> vsw chunk16 [vd-p][n-d]
// ---------------------------------------------------------------------------
__global__ __launch_bounds__(512, 4) void kqv_kernel(
    const float* __restrict__ x, const u16* __restrict__ wA,
    const float* __restrict__ bkq, const float* __restrict__ bv,
    u16* __restrict__ kqh, u16* __restrict__ vsw)
{
    __shared__ __align__(16) u16 lds[20480];   // A(w) 16384 u16 | B(x) 4096 u16
    const int b  = blockIdx.x & 7;
    const int nb = blockIdx.x >> 3;
    const int n0 = nb << 6;
    const int t  = threadIdx.x;
    const int wave = t >> 6, lane = t & 63;
    const int qq = lane >> 4, c_l = lane & 15;

    f32x4 acc[8];
#pragma unroll
    for (int j = 0; j < 8; ++j) acc[j] = (f32x4){0.f, 0.f, 0.f, 0.f};

    for (int ki = 0; ki < 4; ++ki) {
        __syncthreads();
        // stage A (weights c-slice, 32KB) via DMA: 32 chunks, 4/wave
#pragma unroll
        for (int ch = 0; ch < 4; ++ch) {
            const int c = wave * 4 + ch;
            dma16(wA + (c >> 1) * 4096 + ki * 1024 + (c & 1) * 512 + lane * 8,
                  &lds[c * 512]);
        }
        // stage B: x fp32 -> fp16 chunk16, 1 cell/thread (cell = 16B octet)
        {
            const int g = t >> 7, oct = (t >> 4) & 7, p16 = t & 15;
            const int pos = n0 + g * 16 + p16;
            const float* xp = x + (size_t)((b * 256 + ki * 64 + oct * 8) * NN) + pos;
            float v[8];
#pragma unroll
            for (int i = 0; i < 8; ++i) v[i] = xp[(size_t)i * NN];
            const uint2 lo = pk4h(v[0], v[1], v[2], v[3]);
            const uint2 hi = pk4h(v[4], v[5], v[6], v[7]);
            *(uint4*)&lds[16384 + g * 1024 + oct * 128 + p16 * 8] =
                make_uint4(lo.x, lo.y, hi.x, hi.y);
        }
        __syncthreads();

        if (wave < 4) {
#pragma unroll
            for (int ks = 0; ks < 2; ++ks) {
                const half8 a0 = *(const half8*)&lds[(2 * wave) * 1024 + ks * 512 + lane * 8];
                const half8 a1 = *(const half8*)&lds[(2 * wave + 1) * 1024 + ks * 512 + lane * 8];
#pragma unroll
                for (int tn = 0; tn < 4; ++tn) {
                    const half8 bf = *(const half8*)&lds[16384 + tn * 1024 + ks * 512 + lane * 8];
                    acc[tn]     = __builtin_amdgcn_mfma_f32_16x16x32_f16(a0, bf, acc[tn], 0, 0, 0);
                    acc[4 + tn] = __builtin_amdgcn_mfma_f32_16x16x32_f16(a1, bf, acc[4 + tn], 0, 0, 0);
                }
            }
        } else {
            const int w4 = wave - 4;
#pragma unroll
            for (int ks = 0; ks < 2; ++ks) {
                const half8 a0 = *(const half8*)&lds[16384 + w4 * 1024 + ks * 512 + lane * 8];
#pragma unroll
                for (int tn = 0; tn < 8; ++tn) {
                    const half8 bf = *(const half8*)&lds[(8 + tn) * 1024 + ks * 512 + lane * 8];
                    acc[tn] = __builtin_amdgcn_mfma_f32_16x16x32_f16(a0, bf, acc[tn], 0, 0, 0);
                }
            }
        }
    }

    if (wave < 4) {
        // kq: m = (2w+T)*16+qq*4+r, pos = n0+tn*16+c_l; scaled+biased -> kqh
#pragma unroll
        for (int T = 0; T < 2; ++T) {
            const int m0 = (2 * wave + T) * 16 + qq * 4;
            const float4 bq = *(const float4*)&bkq[m0];
            const int rowoff = ((2 * wave + T) * 2 + (qq >> 1)) * 128 + c_l * 8 + (qq & 1) * 4;
#pragma unroll
            for (int tn = 0; tn < 4; ++tn) {
                const f32x4 a = acc[T * 4 + tn];
                *(uint2*)(kqh + b * 524288 + ((n0 >> 4) + tn) * 2048 + rowoff) =
                    pk4h((a[0] + bq.x) * SCALE_S, (a[1] + bq.y) * SCALE_S,
                         (a[2] + bq.z) * SCALE_S, (a[3] + bq.w) * SCALE_S);
            }
        }
    } else {
        const int w4 = wave - 4;
        // v^T: pos = n0+w4*16+qq*4+r, vd = tn*16+c_l -> vsw
        const int posq = n0 + w4 * 16 + qq * 4;
#pragma unroll
        for (int tn = 0; tn < 8; ++tn) {
            const float bias = bv[tn * 16 + c_l];
            *(uint2*)(vsw + b * 524288 + tn * 65536 + (posq >> 3) * 128 + c_l * 8 + (posq & 7)) =
                pk4h(acc[tn][0] + bias, acc[tn][1] + bias,
                     acc[tn][2] + bias, acc[tn][3] + bias);
        }
    }
}

// ---------------------------------------------------------------------------
// Kernel 2: flash attention. BM=64, BN=64, D=128. 4 waves = 2 mw x 2 nw.
// Grid 512 -> 2 independent blocks/CU (phase overlap). Wave shape as R4:
// 32 q-rows (2 colsets) x 32-key half, local online softmax, nw-merge epilogue.
// ---------------------------------------------------------------------------
__global__ __launch_bounds__(256, 2) void flash_kernel(
    const u16* __restrict__ kqh, const u16* __restrict__ vsw,
    u16* __restrict__ ctxh)
{
    // u16: K0 [0,8192) K1 [8192,16384) V [16384,24576) P [24576,28672)
    __shared__ __align__(16) u16 lds[28672];
    const int b  = blockIdx.x & 7;
    const int mt = blockIdx.x >> 3;            // 0..63 (64-row q tile)
    const int t  = threadIdx.x;
    const int wave = t >> 6, lane = t & 63;
    const int qq = lane >> 4, c_l = lane & 15;
    const int mw = wave >> 1, nw = wave & 1;
    const int pbase = 24576 + wave * 1024;
    const u16* kqb = kqh + b * 524288;
    const u16* vb  = vsw + b * 524288;

    // Q B-frags in regs: [cs][ks]
    half8 q[2][4];
#pragma unroll
    for (int cs = 0; cs < 2; ++cs)
#pragma unroll
        for (int ks = 0; ks < 4; ++ks)
            q[cs][ks] = *(const half8*)(kqb + (mt * 4 + mw * 2 + cs) * 2048 + ks * 512 + lane * 8);

    f32x4 o[8][2];
#pragma unroll
    for (int vt = 0; vt < 8; ++vt)
#pragma unroll
        for (int cs = 0; cs < 2; ++cs) o[vt][cs] = (f32x4){0.f, 0.f, 0.f, 0.f};
    float m_s[2] = {-__builtin_inff(), -__builtin_inff()};
    float l_s[2] = {0.f, 0.f};

    // preload K(0): 16 chunks, 4/wave
#pragma unroll
    for (int ch = 0; ch < 4; ++ch) {
        const int c = wave * 4 + ch;
        dma16(kqb + c * 512 + lane * 8, &lds[c * 512]);
    }

    for (int it = 0; it < 64; ++it) {
        const int n0 = it << 6;
        const int kc = (it & 1) << 13;
        __syncthreads();                               // A: K(it) ready, V free
#pragma unroll
        for (int ch = 0; ch < 4; ++ch) {               // V(it): 16 chunks
            const int cc = wave * 4 + ch;
            dma16(vb + (cc >> 1) * 65536 + (n0 >> 3) * 128 + (cc & 1) * 512 + lane * 8,
                  &lds[16384 + cc * 512]);
        }
        if (it < 63) {
#pragma unroll
            for (int ch = 0; ch < 4; ++ch) {           // K(it+1) prefetch
                const int c = wave * 4 + ch;
                dma16(kqb + ((n0 + 64) >> 4) * 2048 + c * 512 + lane * 8,
                      &lds[(kc ^ 8192) + c * 512]);
            }
        }

        // S^T = K·Q^T : rows n (wave's 32-key half), cols m (32 q-rows)
        f32x4 s[2][2];
#pragma unroll
        for (int nrs = 0; nrs < 2; ++nrs)
#pragma unroll
            for (int cs = 0; cs < 2; ++cs) s[nrs][cs] = (f32x4){0.f, 0.f, 0.f, 0.f};
#pragma unroll
        for (int nrs = 0; nrs < 2; ++nrs) {
#pragma unroll
            for (int ks = 0; ks < 4; ++ks) {
                const half8 kf = *(const half8*)&lds[kc + (nw * 2 + nrs) * 2048 + ks * 512 + lane * 8];
                s[nrs][0] = __builtin_amdgcn_mfma_f32_16x16x32_f16(kf, q[0][ks], s[nrs][0], 0, 0, 0);
                s[nrs][1] = __builtin_amdgcn_mfma_f32_16x16x32_f16(kf, q[1][ks], s[nrs][1], 0, 0, 0);
            }
        }

        // local online softmax (base-2); lane state is for column m = cs*16+c_l
        float al[2];
#pragma unroll
        for (int cs = 0; cs < 2; ++cs) {
            float mx = fmaxf(fmaxf(fmaxf(s[0][cs][0], s[0][cs][1]), fmaxf(s[0][cs][2], s[0][cs][3])),
                             fmaxf(fmaxf(s[1][cs][0], s[1][cs][1]), fmaxf(s[1][cs][2], s[1][cs][3])));
            mx = fmaxf(mx, __shfl_xor(mx, 16, 64));
            mx = fmaxf(mx, __shfl_xor(mx, 32, 64));
            const float mn = fmaxf(m_s[cs], mx);
            al[cs] = __builtin_amdgcn_exp2f(m_s[cs] - mn);
            m_s[cs] = mn;
            float ps = 0.f;
#pragma unroll
            for (int nrs = 0; nrs < 2; ++nrs) {
                const float p0 = __builtin_amdgcn_exp2f(s[nrs][cs][0] - mn);
                const float p1 = __builtin_amdgcn_exp2f(s[nrs][cs][1] - mn);
                const float p2 = __builtin_amdgcn_exp2f(s[nrs][cs][2] - mn);
                const float p3 = __builtin_amdgcn_exp2f(s[nrs][cs][3] - mn);
                ps += (p0 + p1) + (p2 + p3);
                *(uint2*)&lds[pbase + cs * 512 + (nrs * 2 + (qq >> 1)) * 128 + c_l * 8 + (qq & 1) * 4] =
                    pk4h(p0, p1, p2, p3);
            }
            l_s[cs] = l_s[cs] * al[cs] + ps;
        }
        if (__any(al[0] < 1.f || al[1] < 1.f)) {
#pragma unroll
            for (int vt = 0; vt < 8; ++vt) {
                o[vt][0] *= al[0];
                o[vt][1] *= al[1];
            }
        }

        __syncthreads();                               // B: V(it) ready
        const half8 pf0 = *(const half8*)&lds[pbase + lane * 8];
        const half8 pf1 = *(const half8*)&lds[pbase + 512 + lane * 8];
#pragma unroll
        for (int vt = 0; vt < 8; ++vt) {
            const half8 vf = *(const half8*)&lds[16384 + vt * 1024 + nw * 512 + lane * 8];
            o[vt][0] = __builtin_amdgcn_mfma_f32_16x16x32_f16(vf, pf0, o[vt][0], 0, 0, 0);
            o[vt][1] = __builtin_amdgcn_mfma_f32_16x16x32_f16(vf, pf1, o[vt][1], 0, 0, 0);
        }
    }

    // ---- epilogue: merge the nw pair ----
#pragma unroll
    for (int cs = 0; cs < 2; ++cs) {
        l_s[cs] += __shfl_xor(l_s[cs], 16, 64);
        l_s[cs] += __shfl_xor(l_s[cs], 32, 64);
    }
    __syncthreads();
    float* mlf = (float*)&lds[24576];
    if (qq == 0) {
#pragma unroll
        for (int cs = 0; cs < 2; ++cs) {
            mlf[((mw * 2 + nw) * 2 + cs) * 32 + c_l * 2]     = m_s[cs];
            mlf[((mw * 2 + nw) * 2 + cs) * 32 + c_l * 2 + 1] = l_s[cs];
        }
    }
    __syncthreads();
    float ga[2], inv[2];
#pragma unroll
    for (int cs = 0; cs < 2; ++cs) {
        const int base = ((mw * 2 + (nw ^ 1)) * 2 + cs) * 32 + c_l * 2;
        const float m2 = mlf[base], l2 = mlf[base + 1];
        const float ms = fmaxf(m_s[cs], m2);
        const float g1 = __builtin_amdgcn_exp2f(m_s[cs] - ms);
        const float g2 = __builtin_amdgcn_exp2f(m2 - ms);
        ga[cs] = g1;
        inv[cs] = 1.f / (l_s[cs] * g1 + l2 * g2);
    }
    __syncthreads();                                    // ml reads done before obuf reuse
    float* obuf = (float*)lds;                          // region mw*4096 floats (32KB in K0/K1)
    if (nw == 1) {
#pragma unroll
        for (int vt = 0; vt < 8; ++vt)
#pragma unroll
            for (int cs = 0; cs < 2; ++cs)
                *(f32x4*)&obuf[mw * 4096 + ((vt * 2 + cs) * 64 + lane) * 4] = o[vt][cs] * ga[cs];
    }
    __syncthreads();
    if (nw == 0) {
        u16* cb = ctxh + b * 524288;
#pragma unroll
        for (int vt = 0; vt < 8; ++vt) {
#pragma unroll
            for (int cs = 0; cs < 2; ++cs) {
                const f32x4 op = *(const f32x4*)&obuf[mw * 4096 + ((vt * 2 + cs) * 64 + lane) * 4];
                const f32x4 oo = (o[vt][cs] * ga[cs] + op) * inv[cs];
                // pos = mt*64+mw*32+cs*16+c_l ; vd = vt*16+qq*4+r
                *(uint2*)(cb + (mt * 4 + mw * 2 + cs) * 2048 + (vt * 2 + (qq >> 1)) * 128 +
                          c_l * 8 + (qq & 1) * 4) = pk4h(oo[0], oo[1], oo[2], oo[3]);
            }
        }
    }
}

// ---------------------------------------------------------------------------
// Kernel 3: out = w_o @ ctx + b_o (fp32). M=256 x N=64, K=128. Grid 512.
// ---------------------------------------------------------------------------
__global__ __launch_bounds__(512, 4) void out_kernel(
    const u16* __restrict__ woh, const u16* __restrict__ ctxh,
    const float* __restrict__ bo, float* __restrict__ out)
{
    __shared__ __align__(16) u16 lds[20480];   // A(wo) 16384 | B(ctx) 4096
    const int b  = blockIdx.x & 7;
    const int nb = blockIdx.x >> 3;
    const int n0 = nb << 6;
    const int t  = threadIdx.x;
    const int wave = t >> 6, lane = t & 63;
    const int qq = lane >> 4, c_l = lane & 15;

    f32x4 acc[2][4];
#pragma unroll
    for (int i = 0; i < 2; ++i)
#pragma unroll
        for (int j = 0; j < 4; ++j) acc[i][j] = (f32x4){0.f, 0.f, 0.f, 0.f};

    for (int ki = 0; ki < 2; ++ki) {
        __syncthreads();
#pragma unroll
        for (int ch = 0; ch < 5; ++ch) {
            const int c = wave * 5 + ch;               // 0..39
            if (c < 32) {
                dma16(woh + (c >> 1) * 2048 + ki * 1024 + (c & 1) * 512 + lane * 8,
                      &lds[c * 512]);
            } else {
                const int cc = c - 32;                 // 0..7
                dma16(ctxh + b * 524288 + ((n0 >> 4) + (cc >> 1)) * 2048 + ki * 1024 +
                          (cc & 1) * 512 + lane * 8,
                      &lds[16384 + cc * 512]);
            }
        }
        __syncthreads();
#pragma unroll
        for (int ks = 0; ks < 2; ++ks) {
            const half8 a0 = *(const half8*)&lds[(2 * wave) * 1024 + ks * 512 + lane * 8];
            const half8 a1 = *(const half8*)&lds[(2 * wave + 1) * 1024 + ks * 512 + lane * 8];
#pragma unroll
            for (int tn = 0; tn < 4; ++tn) {
                const half8 bf = *(const half8*)&lds[16384 + tn * 1024 + ks * 512 + lane * 8];
                acc[0][tn] = __builtin_amdgcn_mfma_f32_16x16x32_f16(a0, bf, acc[0][tn], 0, 0, 0);
                acc[1][tn] = __builtin_amdgcn_mfma_f32_16x16x32_f16(a1, bf, acc[1][tn], 0, 0, 0);
            }
        }
    }

#pragma unroll
    for (int T = 0; T < 2; ++T) {
        const int m0 = (2 * wave + T) * 16 + qq * 4;
        const float4 bq = *(const float4*)&bo[m0];
#pragma unroll
        for (int tn = 0; tn < 4; ++tn) {
            const int pos = n0 + tn * 16 + c_l;
            out[(size_t)((b * 256 + m0 + 0) * NN) + pos] = acc[T][tn][0] + bq.x;
            out[(size_t)((b * 256 + m0 + 1) * NN) + pos] = acc[T][tn][1] + bq.y;
            out[(size_t)((b * 256 + m0 + 2) * NN) + pos] = acc[T][tn][2] + bq.z;
            out[(size_t)((b * 256 + m0 + 3) * NN) + pos] = acc[T][tn][3] + bq.w;
        }
    }
}

// ---------------------------------------------------------------------------
extern "C" void kernel_launch(void* const* d_in, const int* in_sizes, int n_in,
                              void* d_out, int out_size, void* d_ws, size_t ws_size,
                              hipStream_t stream) {
    const float* x    = (const float*)d_in[0];
    const float* w_kq = (const float*)d_in[1];
    const float* b_kq = (const float*)d_in[2];
    const float* w_v  = (const float*)d_in[3];
    const float* b_v  = (const float*)d_in[4];
    const float* w_o  = (const float*)d_in[5];
    const float* b_o  = (const float*)d_in[6];
    float* out = (float*)d_out;

    // ws: kqh 8MB | vsw 8MB | ctxh 8MB | wA 128KB | woh 64KB
    u16* kqh  = (u16*)d_ws;
    u16* vsw  = (u16*)((char*)d_ws + (8u << 20));
    u16* ctxh = (u16*)((char*)d_ws + (16u << 20));
    u16* wA   = (u16*)((char*)d_ws + (24u << 20));
    u16* woh  = wA + 65536;

    wcast_kernel<<<dim3(48), dim3(256), 0, stream>>>(w_kq, w_v, w_o, wA, woh);
    kqv_kernel<<<dim3(512), dim3(512), 0, stream>>>(x, wA, b_kq, b_v, kqh, vsw);
    flash_kernel<<<dim3(512), dim3(256), 0, stream>>>(kqh, vsw, ctxh);
    out_kernel<<<dim3(512), dim3(512), 0, stream>>>(woh, ctxh, b_o, out);
}

// Round 6
// 192.385 us; speedup vs baseline: 1.0737x; 1.0737x over previous
//
#include <hip/hip_runtime.h>
#include <stdint.h>

typedef unsigned short u16;
typedef _Float16 half8 __attribute__((ext_vector_type(8)));
typedef float    f32x4 __attribute__((ext_vector_type(4)));

#define NN 4096
#define SCALE_S 1.2011224087f   // sqrt(log2 e): applied to kq once -> logits in log2 domain

__device__ __forceinline__ u16 f2h(float f) {
    _Float16 h = (_Float16)f;
    return __builtin_bit_cast(u16, h);
}
__device__ __forceinline__ unsigned int pk(u16 a, u16 b) {
    return (unsigned int)a | ((unsigned int)b << 16);
}
__device__ __forceinline__ uint2 pk4h(float a, float b, float c, float d) {
    uint2 r;
    r.x = __builtin_bit_cast(unsigned int, __builtin_amdgcn_cvt_pkrtz(a, b));
    r.y = __builtin_bit_cast(unsigned int, __builtin_amdgcn_cvt_pkrtz(c, d));
    return r;
}
__device__ __forceinline__ void dma16(const u16* src, const u16* dst) {
    __builtin_amdgcn_global_load_lds(
        (const __attribute__((address_space(1))) uint32_t*)src,
        (__attribute__((address_space(3))) uint32_t*)dst, 16, 0, 0);
}

// chunk16 layout for M[d][p] (d = K-dim, inner-8): el = (p>>4)*(2*D) + (d>>3)*128 + (p&15)*8 + (d&7)

// ---------------------------------------------------------------------------
// Kernel 0: weights fp32 -> fp16 chunk16. wA=[w_kq;w_v] [256 m][256 c]; wo [256][128].
// ---------------------------------------------------------------------------
__global__ __launch_bounds__(256) void wcast_kernel(
    const float* __restrict__ wkq, const float* __restrict__ wv,
    const float* __restrict__ wo, u16* __restrict__ wA, u16* __restrict__ woh)
{
    const int gid = blockIdx.x * 256 + threadIdx.x;   // 12288 total
    if (gid < 8192) {
        const int m = gid >> 5, co = gid & 31;
        const float* src = (m < 128) ? &wkq[m * 256 + co * 8] : &wv[(m - 128) * 256 + co * 8];
        u16 h[8];
#pragma unroll
        for (int i = 0; i < 8; ++i) h[i] = f2h(src[i]);
        *(uint4*)(wA + (m >> 4) * 4096 + co * 128 + (m & 15) * 8) =
            make_uint4(pk(h[0],h[1]), pk(h[2],h[3]), pk(h[4],h[5]), pk(h[6],h[7]));
    } else {
        const int u = gid - 8192;
        const int m = u >> 4, co = u & 15;
        const float* src = &wo[m * 128 + co * 8];
        u16 h[8];
#pragma unroll
        for (int i = 0; i < 8; ++i) h[i] = f2h(src[i]);
        *(uint4*)(woh + (m >> 4) * 2048 + co * 128 + (m & 15) * 8) =
            make_uint4(pk(h[0],h[1]), pk(h[2],h[3]), pk(h[4],h[5]), pk(h[6],h[7]));
    }
}

// ---------------------------------------------------------------------------
// Kernel 1: [kq ; v] = wA @ x + bias. M=256 x N=64 pos, K=256 over 4 iters.
// x ingested via coalesced 256B float4 runs -> fp32 LDS scratch -> pack fp16.
// ---------------------------------------------------------------------------
__global__ __launch_bounds__(512, 4) void kqv_kernel(
    const float* __restrict__ x, const u16* __restrict__ wA,
    const float* __restrict__ bkq, const float* __restrict__ bv,
    u16* __restrict__ kqh, u16* __restrict__ vsw)
{
    // u16: A [0,16384) Bpack [16384,20480) ; fp32 scratch at byte 40960: 64 rows x 68
    __shared__ __align__(16) u16 lds[29184];
    float* scr = (float*)&lds[20480];
    const int b  = blockIdx.x & 7;
    const int nb = blockIdx.x >> 3;
    const int n0 = nb << 6;
    const int t  = threadIdx.x;
    const int wave = t >> 6, lane = t & 63;
    const int qq = lane >> 4, c_l = lane & 15;

    f32x4 acc[8];
#pragma unroll
    for (int j = 0; j < 8; ++j) acc[j] = (f32x4){0.f, 0.f, 0.f, 0.f};

    for (int ki = 0; ki < 4; ++ki) {
        __syncthreads();                       // prev MFMA reads done
        // stage A (weights c-slice, 32KB) via DMA: 32 chunks, 4/wave
#pragma unroll
        for (int ch = 0; ch < 4; ++ch) {
            const int c = wave * 4 + ch;
            dma16(wA + (c >> 1) * 4096 + ki * 1024 + (c & 1) * 512 + lane * 8,
                  &lds[c * 512]);
        }
        // x pos-major coalesced -> scratch (row = channel, 64 pos)
        {
            const int row = t >> 3, seg = t & 7;
            const float* xp = x + (size_t)((b * 256 + ki * 64 + row) * NN) + n0 + seg * 8;
            const float4 xa = *(const float4*)xp;
            const float4 xb = *(const float4*)(xp + 4);
            *(float4*)&scr[row * 68 + seg * 8]     = xa;
            *(float4*)&scr[row * 68 + seg * 8 + 4] = xb;
        }
        __syncthreads();                       // scratch ready, A drained
        // pack: 1 chunk16 cell/thread
        {
            const int g = t >> 7, oct = (t >> 4) & 7, p16 = t & 15;
            const int pl = g * 16 + p16;
            float v[8];
#pragma unroll
            for (int i = 0; i < 8; ++i) v[i] = scr[(oct * 8 + i) * 68 + pl];
            const uint2 lo = pk4h(v[0], v[1], v[2], v[3]);
            const uint2 hi = pk4h(v[4], v[5], v[6], v[7]);
            *(uint4*)&lds[16384 + g * 1024 + oct * 128 + p16 * 8] =
                make_uint4(lo.x, lo.y, hi.x, hi.y);
        }
        __syncthreads();                       // Bpack ready

        if (wave < 4) {
#pragma unroll
            for (int ks = 0; ks < 2; ++ks) {
                const half8 a0 = *(const half8*)&lds[(2 * wave) * 1024 + ks * 512 + lane * 8];
                const half8 a1 = *(const half8*)&lds[(2 * wave + 1) * 1024 + ks * 512 + lane * 8];
#pragma unroll
                for (int tn = 0; tn < 4; ++tn) {
                    const half8 bf = *(const half8*)&lds[16384 + tn * 1024 + ks * 512 + lane * 8];
                    acc[tn]     = __builtin_amdgcn_mfma_f32_16x16x32_f16(a0, bf, acc[tn], 0, 0, 0);
                    acc[4 + tn] = __builtin_amdgcn_mfma_f32_16x16x32_f16(a1, bf, acc[4 + tn], 0, 0, 0);
                }
            }
        } else {
            const int w4 = wave - 4;
#pragma unroll
            for (int ks = 0; ks < 2; ++ks) {
                const half8 a0 = *(const half8*)&lds[16384 + w4 * 1024 + ks * 512 + lane * 8];
#pragma unroll
                for (int tn = 0; tn < 8; ++tn) {
                    const half8 bf = *(const half8*)&lds[(8 + tn) * 1024 + ks * 512 + lane * 8];
                    acc[tn] = __builtin_amdgcn_mfma_f32_16x16x32_f16(a0, bf, acc[tn], 0, 0, 0);
                }
            }
        }
    }

    if (wave < 4) {
#pragma unroll
        for (int T = 0; T < 2; ++T) {
            const int m0 = (2 * wave + T) * 16 + qq * 4;
            const float4 bq = *(const float4*)&bkq[m0];
            const int rowoff = ((2 * wave + T) * 2 + (qq >> 1)) * 128 + c_l * 8 + (qq & 1) * 4;
#pragma unroll
            for (int tn = 0; tn < 4; ++tn) {
                const f32x4 a = acc[T * 4 + tn];
                *(uint2*)(kqh + b * 524288 + ((n0 >> 4) + tn) * 2048 + rowoff) =
                    pk4h((a[0] + bq.x) * SCALE_S, (a[1] + bq.y) * SCALE_S,
                         (a[2] + bq.z) * SCALE_S, (a[3] + bq.w) * SCALE_S);
            }
        }
    } else {
        const int w4 = wave - 4;
        const int posq = n0 + w4 * 16 + qq * 4;
#pragma unroll
        for (int tn = 0; tn < 8; ++tn) {
            const float bias = bv[tn * 16 + c_l];
            *(uint2*)(vsw + b * 524288 + tn * 65536 + (posq >> 3) * 128 + c_l * 8 + (posq & 7)) =
                pk4h(acc[tn][0] + bias, acc[tn][1] + bias,
                     acc[tn][2] + bias, acc[tn][3] + bias);
        }
    }
}

// ---------------------------------------------------------------------------
// Kernel 2: flash attention. BM=64, BN=64, D=128. 4 waves = 2 mw x 2 nw.
// ONE barrier/iter: V double-buffered via DMA; K frags direct global->regs
// (ping-pong prefetch); P wave-local in LDS (no barrier on its round-trip).
// ---------------------------------------------------------------------------
__global__ __launch_bounds__(256, 2) void flash_kernel(
    const u16* __restrict__ kqh, const u16* __restrict__ vsw,
    u16* __restrict__ ctxh)
{
    // u16: V0 [0,8192) V1 [8192,16384) P [16384,20480)
    __shared__ __align__(16) u16 lds[20480];
    const int b  = blockIdx.x & 7;
    const int mt = blockIdx.x >> 3;            // 0..63
    const int t  = threadIdx.x;
    const int wave = t >> 6, lane = t & 63;
    const int qq = lane >> 4, c_l = lane & 15;
    const int mw = wave >> 1, nw = wave & 1;
    const int pbase = 16384 + wave * 1024;
    const u16* kqb = kqh + b * 524288;
    const u16* vb  = vsw + b * 524288;

    // Q B-frags in regs: [cs][ks]
    half8 q[2][4];
#pragma unroll
    for (int cs = 0; cs < 2; ++cs)
#pragma unroll
        for (int ks = 0; ks < 4; ++ks)
            q[cs][ks] = *(const half8*)(kqb + (mt * 4 + mw * 2 + cs) * 2048 + ks * 512 + lane * 8);

    f32x4 o[8][2];
#pragma unroll
    for (int vt = 0; vt < 8; ++vt)
#pragma unroll
        for (int cs = 0; cs < 2; ++cs) o[vt][cs] = (f32x4){0.f, 0.f, 0.f, 0.f};
    float m_s[2] = {-__builtin_inff(), -__builtin_inff()};
    float l_s[2] = {0.f, 0.f};

    // prologue: DMA V(0) -> buf0; K(0) frags -> regs
#pragma unroll
    for (int ch = 0; ch < 4; ++ch) {
        const int cc = wave * 4 + ch;
        dma16(vb + (cc >> 1) * 65536 + (cc & 1) * 512 + lane * 8, &lds[cc * 512]);
    }
    half8 kfa[2][4], kfb[2][4];
#pragma unroll
    for (int nrs = 0; nrs < 2; ++nrs)
#pragma unroll
        for (int ks = 0; ks < 4; ++ks)
            kfa[nrs][ks] = *(const half8*)(kqb + (nw * 2 + nrs) * 2048 + ks * 512 + lane * 8);

    auto body = [&](int it, half8 (&kf)[2][4], half8 (&kfn)[2][4]) {
        const int n0 = it << 6;
        const int vcur = (it & 1) << 13;       // u16 idx 0 or 8192
        __syncthreads();                       // V(it) staged, K(it) in regs
        if (it < 63) {
            const int n1 = n0 + 64;
#pragma unroll
            for (int ch = 0; ch < 4; ++ch) {   // DMA V(it+1) -> other buf
                const int cc = wave * 4 + ch;
                dma16(vb + (cc >> 1) * 65536 + (n1 >> 3) * 128 + (cc & 1) * 512 + lane * 8,
                      &lds[(vcur ^ 8192) + cc * 512]);
            }
        }
        // S^T = K·Q^T
        f32x4 s[2][2];
#pragma unroll
        for (int nrs = 0; nrs < 2; ++nrs)
#pragma unroll
            for (int cs = 0; cs < 2; ++cs) s[nrs][cs] = (f32x4){0.f, 0.f, 0.f, 0.f};
#pragma unroll
        for (int nrs = 0; nrs < 2; ++nrs) {
#pragma unroll
            for (int ks = 0; ks < 4; ++ks) {
                s[nrs][0] = __builtin_amdgcn_mfma_f32_16x16x32_f16(kf[nrs][ks], q[0][ks], s[nrs][0], 0, 0, 0);
                s[nrs][1] = __builtin_amdgcn_mfma_f32_16x16x32_f16(kf[nrs][ks], q[1][ks], s[nrs][1], 0, 0, 0);
            }
        }
        // prefetch K(it+1) -> other reg set (hidden behind softmax+PV)
        if (it < 63) {
            const int n1 = n0 + 64;
#pragma unroll
            for (int nrs = 0; nrs < 2; ++nrs)
#pragma unroll
                for (int ks = 0; ks < 4; ++ks)
                    kfn[nrs][ks] = *(const half8*)(kqb + ((n1 >> 4) + nw * 2 + nrs) * 2048 + ks * 512 + lane * 8);
        }

        // local online softmax (base-2); lane state is column m = cs*16+c_l
        float al[2];
#pragma unroll
        for (int cs = 0; cs < 2; ++cs) {
            float mx = fmaxf(fmaxf(fmaxf(s[0][cs][0], s[0][cs][1]), fmaxf(s[0][cs][2], s[0][cs][3])),
                             fmaxf(fmaxf(s[1][cs][0], s[1][cs][1]), fmaxf(s[1][cs][2], s[1][cs][3])));
            mx = fmaxf(mx, __shfl_xor(mx, 16, 64));
            mx = fmaxf(mx, __shfl_xor(mx, 32, 64));
            const float mn = fmaxf(m_s[cs], mx);
            al[cs] = __builtin_amdgcn_exp2f(m_s[cs] - mn);
            m_s[cs] = mn;
            float ps = 0.f;
#pragma unroll
            for (int nrs = 0; nrs < 2; ++nrs) {
                const float p0 = __builtin_amdgcn_exp2f(s[nrs][cs][0] - mn);
                const float p1 = __builtin_amdgcn_exp2f(s[nrs][cs][1] - mn);
                const float p2 = __builtin_amdgcn_exp2f(s[nrs][cs][2] - mn);
                const float p3 = __builtin_amdgcn_exp2f(s[nrs][cs][3] - mn);
                ps += (p0 + p1) + (p2 + p3);
                *(uint2*)&lds[pbase + cs * 512 + (nrs * 2 + (qq >> 1)) * 128 + c_l * 8 + (qq & 1) * 4] =
                    pk4h(p0, p1, p2, p3);
            }
            l_s[cs] = l_s[cs] * al[cs] + ps;
        }
        if (__any(al[0] < 1.f || al[1] < 1.f)) {
#pragma unroll
            for (int vt = 0; vt < 8; ++vt) {
                o[vt][0] *= al[0];
                o[vt][1] *= al[1];
            }
        }

        // O += P V  (P wave-local: no barrier, lgkm ordering within wave)
        const half8 pf0 = *(const half8*)&lds[pbase + lane * 8];
        const half8 pf1 = *(const half8*)&lds[pbase + 512 + lane * 8];
#pragma unroll
        for (int vt = 0; vt < 8; ++vt) {
            const half8 vf = *(const half8*)&lds[vcur + vt * 1024 + nw * 512 + lane * 8];
            o[vt][0] = __builtin_amdgcn_mfma_f32_16x16x32_f16(vf, pf0, o[vt][0], 0, 0, 0);
            o[vt][1] = __builtin_amdgcn_mfma_f32_16x16x32_f16(vf, pf1, o[vt][1], 0, 0, 0);
        }
    };

    for (int it2 = 0; it2 < 32; ++it2) {
        body(2 * it2,     kfa, kfb);
        body(2 * it2 + 1, kfb, kfa);
    }

    // ---- epilogue: merge the nw pair ----
#pragma unroll
    for (int cs = 0; cs < 2; ++cs) {
        l_s[cs] += __shfl_xor(l_s[cs], 16, 64);
        l_s[cs] += __shfl_xor(l_s[cs], 32, 64);
    }
    __syncthreads();
    float* mlf = (float*)&lds[16384];          // P region reuse
    if (qq == 0) {
#pragma unroll
        for (int cs = 0; cs < 2; ++cs) {
            mlf[((mw * 2 + nw) * 2 + cs) * 32 + c_l * 2]     = m_s[cs];
            mlf[((mw * 2 + nw) * 2 + cs) * 32 + c_l * 2 + 1] = l_s[cs];
        }
    }
    __syncthreads();
    float ga[2], inv[2];
#pragma unroll
    for (int cs = 0; cs < 2; ++cs) {
        const int base = ((mw * 2 + (nw ^ 1)) * 2 + cs) * 32 + c_l * 2;
        const float m2 = mlf[base], l2 = mlf[base + 1];
        const float ms = fmaxf(m_s[cs], m2);
        const float g1 = __builtin_amdgcn_exp2f(m_s[cs] - ms);
        const float g2 = __builtin_amdgcn_exp2f(m2 - ms);
        ga[cs] = g1;
        inv[cs] = 1.f / (l_s[cs] * g1 + l2 * g2);
    }
    __syncthreads();
    float* obuf = (float*)lds;                 // V region reuse (32 KB)
    if (nw == 1) {
#pragma unroll
        for (int vt = 0; vt < 8; ++vt)
#pragma unroll
            for (int cs = 0; cs < 2; ++cs)
                *(f32x4*)&obuf[mw * 4096 + ((vt * 2 + cs) * 64 + lane) * 4] = o[vt][cs] * ga[cs];
    }
    __syncthreads();
    if (nw == 0) {
        u16* cb = ctxh + b * 524288;
#pragma unroll
        for (int vt = 0; vt < 8; ++vt) {
#pragma unroll
            for (int cs = 0; cs < 2; ++cs) {
                const f32x4 op = *(const f32x4*)&obuf[mw * 4096 + ((vt * 2 + cs) * 64 + lane) * 4];
                const f32x4 oo = (o[vt][cs] * ga[cs] + op) * inv[cs];
                *(uint2*)(cb + (mt * 4 + mw * 2 + cs) * 2048 + (vt * 2 + (qq >> 1)) * 128 +
                          c_l * 8 + (qq & 1) * 4) = pk4h(oo[0], oo[1], oo[2], oo[3]);
            }
        }
    }
}

// ---------------------------------------------------------------------------
// Kernel 3: out = w_o @ ctx + b_o (fp32). M=256 x N=64, K=128. Grid 512.
// ---------------------------------------------------------------------------
__global__ __launch_bounds__(512, 4) void out_kernel(
    const u16* __restrict__ woh, const u16* __restrict__ ctxh,
    const float* __restrict__ bo, float* __restrict__ out)
{
    __shared__ __align__(16) u16 lds[20480];   // A(wo) 16384 | B(ctx) 4096
    const int b  = blockIdx.x & 7;
    const int nb = blockIdx.x >> 3;
    const int n0 = nb << 6;
    const int t  = threadIdx.x;
    const int wave = t >> 6, lane = t & 63;
    const int qq = lane >> 4, c_l = lane & 15;

    f32x4 acc[2][4];
#pragma unroll
    for (int i = 0; i < 2; ++i)
#pragma unroll
        for (int j = 0; j < 4; ++j) acc[i][j] = (f32x4){0.f, 0.f, 0.f, 0.f};

    for (int ki = 0; ki < 2; ++ki) {
        __syncthreads();
#pragma unroll
        for (int ch = 0; ch < 5; ++ch) {
            const int c = wave * 5 + ch;               // 0..39
            if (c < 32) {
                dma16(woh + (c >> 1) * 2048 + ki * 1024 + (c & 1) * 512 + lane * 8,
                      &lds[c * 512]);
            } else {
                const int cc = c - 32;                 // 0..7
                dma16(ctxh + b * 524288 + ((n0 >> 4) + (cc >> 1)) * 2048 + ki * 1024 +
                          (cc & 1) * 512 + lane * 8,
                      &lds[16384 + cc * 512]);
            }
        }
        __syncthreads();
#pragma unroll
        for (int ks = 0; ks < 2; ++ks) {
            const half8 a0 = *(const half8*)&lds[(2 * wave) * 1024 + ks * 512 + lane * 8];
            const half8 a1 = *(const half8*)&lds[(2 * wave + 1) * 1024 + ks * 512 + lane * 8];
#pragma unroll
            for (int tn = 0; tn < 4; ++tn) {
                const half8 bf = *(const half8*)&lds[16384 + tn * 1024 + ks * 512 + lane * 8];
                acc[0][tn] = __builtin_amdgcn_mfma_f32_16x16x32_f16(a0, bf, acc[0][tn], 0, 0, 0);
                acc[1][tn] = __builtin_amdgcn_mfma_f32_16x16x32_f16(a1, bf, acc[1][tn], 0, 0, 0);
            }
        }
    }

#pragma unroll
    for (int T = 0; T < 2; ++T) {
        const int m0 = (2 * wave + T) * 16 + qq * 4;
        const float4 bq = *(const float4*)&bo[m0];
#pragma unroll
        for (int tn = 0; tn < 4; ++tn) {
            const int pos = n0 + tn * 16 + c_l;
            out[(size_t)((b * 256 + m0 + 0) * NN) + pos] = acc[T][tn][0] + bq.x;
            out[(size_t)((b * 256 + m0 + 1) * NN) + pos] = acc[T][tn][1] + bq.y;
            out[(size_t)((b * 256 + m0 + 2) * NN) + pos] = acc[T][tn][2] + bq.z;
            out[(size_t)((b * 256 + m0 + 3) * NN) + pos] = acc[T][tn][3] + bq.w;
        }
    }
}

// ---------------------------------------------------------------------------
extern "C" void kernel_launch(void* const* d_in, const int* in_sizes, int n_in,
                              void* d_out, int out_size, void* d_ws, size_t ws_size,
                              hipStream_t stream) {
    const float* x    = (const float*)d_in[0];
    const float* w_kq = (const float*)d_in[1];
    const float* b_kq = (const float*)d_in[2];
    const float* w_v  = (const float*)d_in[3];
    const float* b_v  = (const float*)d_in[4];
    const float* w_o  = (const float*)d_in[5];
    const float* b_o  = (const float*)d_in[6];
    float* out = (float*)d_out;

    u16* kqh  = (u16*)d_ws;
    u16* vsw  = (u16*)((char*)d_ws + (8u << 20));
    u16* ctxh = (u16*)((char*)d_ws + (16u << 20));
    u16* wA   = (u16*)((char*)d_ws + (24u << 20));
    u16* woh  = wA + 65536;

    wcast_kernel<<<dim3(48), dim3(256), 0, stream>>>(w_kq, w_v, w_o, wA, woh);
    kqv_kernel<<<dim3(512), dim3(512), 0, stream>>>(x, wA, b_kq, b_v, kqh, vsw);
    flash_kernel<<<dim3(512), dim3(256), 0, stream>>>(kqh, vsw, ctxh);
    out_kernel<<<dim3(512), dim3(512), 0, stream>>>(woh, ctxh, b_o, out);
}